// Round 20
// baseline (35.915 us; speedup 1.0000x reference)
//
#include <hip/hip_runtime.h>
#include <hip/hip_bf16.h>

// NormalizedCutLoss v16 = v15 + ONE change: per chunk, issue ALL FOUR ds_reads
// (both jtl's ag/al) in named registers right after the barrier, then compute.
// Exposes one LDS round-trip per chunk instead of two.
// CODEGEN CLIFF NOTES (v8/v11/v12): NO prefetch arrays with runtime index,
// NO outer pass loop, NO one-shot whole-tile staging, NO launch_bounds(256,4).

#define NIMG 8
#define KSEG 21
#define PIX 4096
#define HI 128
#define WI 128
#define RW 64              // shorts per pixel per side
#define LROW 72            // LDS row stride in shorts (144B)
#define JCH 32             // A-rows per staged chunk
#define NCH 4              // 128 rows / 32
#define NBLK (NIMG * 272)  // 2176
#define LOG2E 1.4426950408889634f
#define BF1 ((unsigned)0x3F80)

typedef __attribute__((ext_vector_type(8))) short s8v;
typedef __attribute__((ext_vector_type(4))) float f4v;

__device__ inline float fast_exp2(float x) {
#if __has_builtin(__builtin_amdgcn_exp2f)
    return __builtin_amdgcn_exp2f(x);
#else
    return exp2f(x);
#endif
}

__device__ inline void hilo_us(float x, unsigned& h, unsigned& l) {
    __hip_bfloat16 hb = __float2bfloat16(x);
    __hip_bfloat16 lb = __float2bfloat16(x - __bfloat162float(hb));
    h = __bfloat16_as_ushort(hb);
    l = __bfloat16_as_ushort(lb);
}
__device__ inline unsigned bf16u(float x) {
    return __bfloat16_as_ushort(__float2bfloat16(x));
}
__device__ inline int pk(unsigned lo, unsigned hi) { return (int)(lo | (hi << 16)); }

__device__ inline void decode_tile(int bid, int& img, int& I, int& J, int& jh, bool& diag) {
    img = bid & 7;
    int rest = bid >> 3;
    int tp = rest >> 1; jh = rest & 1;
    if (tp >= 120) { I = J = tp - 120; diag = true; }
    else {
        diag = false;
        int t = tp; I = 0;
        while (t >= 15 - I) { t -= 15 - I; ++I; }
        J = I + 1 + t;
    }
}

// ---- prep: 8 threads per pixel, 32 pixels per 256-thread block (v10 verbatim) ----
__global__ __launch_bounds__(256)
void prep_kernel(const float* __restrict__ images,
                 const float* __restrict__ segs,
                 const float* __restrict__ rois,
                 short* __restrict__ AJ,
                 short* __restrict__ BI,
                 float* __restrict__ stotF) {
    __shared__ short svL[32][24];
    int tid = threadIdx.x;
    int pxl = tid >> 3, t = tid & 7;
    int p = blockIdx.x * 32 + pxl;
    int img = p >> 12, pp = p & 4095;
    int y = pp >> 6, x = pp & 63;
    int yi = 2 * y, xi = 2 * x;

    float roi = rois[((size_t)img * HI + yi) * WI + xi];

    const float* sbase = segs + (size_t)img * KSEG * HI * WI + (size_t)yi * WI + xi;
    float sv0, sv1, sv2 = 0.0f;
    {
        const float2* s2 = (const float2*)(sbase + (size_t)t * HI * WI);
        float2 a = s2[0], b = s2[WI / 2];
        sv0 = 0.25f * ((a.x + a.y) + (b.x + b.y)) * roi;
    }
    {
        const float2* s2 = (const float2*)(sbase + (size_t)(t + 8) * HI * WI);
        float2 a = s2[0], b = s2[WI / 2];
        sv1 = 0.25f * ((a.x + a.y) + (b.x + b.y)) * roi;
    }
    if (t < 5) {
        const float2* s2 = (const float2*)(sbase + (size_t)(t + 16) * HI * WI);
        float2 a = s2[0], b = s2[WI / 2];
        sv2 = 0.25f * ((a.x + a.y) + (b.x + b.y)) * roi;
    }
    float st = sv0 + sv1 + sv2;
    st += __shfl_xor(st, 1);
    st += __shfl_xor(st, 2);
    st += __shfl_xor(st, 4);
    if (t == 0) stotF[p] = st;

    svL[pxl][t] = (short)bf16u(sv0);
    svL[pxl][t + 8] = (short)bf16u(sv1);
    if (t < 5) svL[pxl][t + 16] = (short)bf16u(sv2);
    if (t == 7) { svL[pxl][21] = 0; svL[pxl][22] = 0; svL[pxl][23] = 0; }

    const float* im = images + (size_t)img * 3 * HI * WI;
    float f0 = im[yi * WI + xi] * (1.0f / 15.0f);
    float f1 = im[HI * WI + yi * WI + xi] * (1.0f / 15.0f);
    float f2 = im[2 * HI * WI + yi * WI + xi] * (1.0f / 15.0f);
    float f3 = (float)x * (1.0f / 40.0f);
    float f4 = (float)y * (1.0f / 40.0f);
    float sq = f0*f0 + f1*f1 + f2*f2 + f3*f3 + f4*f4;
    float q = -0.5f * sq * LOG2E;
    unsigned qh, ql; hilo_us(q, qh, ql);
    unsigned fh[5], fl[5], gh[5], gl[5];
    float fa[5] = {f0, f1, f2, f3, f4};
    #pragma unroll
    for (int c = 0; c < 5; ++c) {
        hilo_us(fa[c], fh[c], fl[c]);
        hilo_us(fa[c] * LOG2E, gh[c], gl[c]);
    }

    int4 zq = {0, 0, 0, 0};
    int4 qA0 = { pk(gh[0],gh[1]), pk(gh[2],gh[3]), pk(gh[4],gl[0]), pk(gl[1],gl[2]) };
    int4 qA1 = { pk(gl[3],gl[4]), pk(gh[0],gh[1]), pk(gh[2],gh[3]), pk(gh[4],BF1) };
    int4 qA2 = { pk(BF1,qh), pk(ql,0), 0, 0 };
    int4 qB0 = { pk(fh[0],fh[1]), pk(fh[2],fh[3]), pk(fh[4],fh[0]), pk(fh[1],fh[2]) };
    int4 qB1 = { pk(fh[3],fh[4]), pk(fl[0],fl[1]), pk(fl[2],fl[3]), pk(fl[4],qh) };
    int4 qB2 = { pk(ql,BF1), pk(BF1,0), 0, 0 };

    __syncthreads();

    int tg = (t < 3) ? t : 0;
    int4 gq = *(const int4*)(&svL[pxl][tg * 8]);

    int4 outA = (t < 3) ? gq : (t == 4) ? qA0 : (t == 5) ? qA1 : (t == 6) ? qA2 : zq;
    int4 outB = (t < 3) ? gq : (t == 4) ? qB0 : (t == 5) ? qB1 : (t == 6) ? qB2 : zq;

    *(int4*)(AJ + (size_t)p * RW + t * 8) = outA;
    *(int4*)(BI + (size_t)p * RW + t * 8) = outB;
}

// ---- pair v16 = v15 + all-4 ds_reads issued immediately after barrier ----
__global__ __launch_bounds__(256, 3)
void pair_kernel(const short* __restrict__ AJ,
                 const short* __restrict__ BI,
                 const float* __restrict__ stotF,
                 float2* __restrict__ partials) {
    __shared__ __align__(16) short stage[2][JCH * LROW];
    __shared__ float red[2][4];

    int tid = threadIdx.x, lane = tid & 63, wv = tid >> 6;
    int c = lane & 15, sg = lane >> 4;
    int img, I, J, jh; bool diag;
    decode_tile(blockIdx.x, img, I, J, jh, diag);
    size_t ibase = (size_t)img * PIX + I * 256;
    size_t jbase = (size_t)img * PIX + J * 256 + jh * 128;
    int i0 = wv * 64;

    s8v bg[4], bl[4];
    float stc[4];
    #pragma unroll
    for (int r = 0; r < 4; ++r) {
        const short* bp = BI + (ibase + i0 + r * 16 + c) * RW;
        bg[r] = *(const s8v*)(bp + sg * 8);
        bl[r] = *(const s8v*)(bp + 32 + sg * 8);
        stc[r] = stotF[ibase + i0 + r * 16 + c];
    }

    const short* ajg = AJ + jbase * RW;
    const float* stjp = stotF + jbase + sg * 4;
    f4v zf = {0.0f, 0.0f, 0.0f, 0.0f};

    int row0 = tid >> 3, ch0 = tid & 7;
    auto stage_chunk = [&](int chk, int buf) {
        const short* base = ajg + (size_t)chk * JCH * RW;
        *(float4*)(&stage[buf][row0 * LROW + ch0 * 8]) =
            *(const float4*)(base + row0 * RW + ch0 * 8);
    };

    float num[4] = {0,0,0,0}, den[4] = {0,0,0,0};

    stage_chunk(0, 0);
    f4v sjc0 = diag ? zf : *(const f4v*)(stjp);
    f4v sjc1 = diag ? zf : *(const f4v*)(stjp + 16);

    for (int chk = 0; chk < NCH; ++chk) {
        int buf = chk & 1;
        __syncthreads();
        // Issue all four LDS reads for this chunk up front (named regs).
        const short* rb0 = &stage[buf][c * LROW];
        const short* rb1 = &stage[buf][(16 + c) * LROW];
        s8v ag0 = *(const s8v*)(rb0 + sg * 8);
        s8v al0 = *(const s8v*)(rb0 + 32 + sg * 8);
        s8v ag1 = *(const s8v*)(rb1 + sg * 8);
        s8v al1 = *(const s8v*)(rb1 + 32 + sg * 8);

        f4v sjn0 = zf, sjn1 = zf;
        if (chk + 1 < NCH) {
            stage_chunk(chk + 1, buf ^ 1);
            if (!diag) {
                sjn0 = *(const f4v*)(stjp + (chk + 1) * 32);
                sjn1 = *(const f4v*)(stjp + (chk + 1) * 32 + 16);
            }
        }

        #pragma unroll
        for (int jtl = 0; jtl < 2; ++jtl) {
            s8v ag = (jtl == 0) ? ag0 : ag1;
            s8v al = (jtl == 0) ? al0 : al1;
            f4v stj4 = (jtl == 0) ? sjc0 : sjc1;

            f4v z = {0, 0, 0, 0};
            f4v g[4], lw[4];
            #pragma unroll
            for (int r = 0; r < 4; ++r) g[r]  = __builtin_amdgcn_mfma_f32_16x16x32_bf16(ag, bg[r], z, 0, 0, 0);
            #pragma unroll
            for (int r = 0; r < 4; ++r) lw[r] = __builtin_amdgcn_mfma_f32_16x16x32_bf16(al, bl[r], z, 0, 0, 0);

            #pragma unroll
            for (int r = 0; r < 4; ++r) {
                #pragma unroll
                for (int qd = 0; qd < 4; ++qd) {
                    float w = fast_exp2(lw[r][qd]);
                    num[r] = fmaf(w, g[r][qd], num[r]);
                    den[r] = fmaf(w, stc[r] + stj4[qd], den[r]);
                }
            }
        }
        sjc0 = sjn0; sjc1 = sjn1;
    }

    float numt = (num[0] + num[1]) + (num[2] + num[3]);
    float dent = (den[0] + den[1]) + (den[2] + den[3]);
    if (!diag) numt *= 2.0f;

    #pragma unroll
    for (int off = 32; off; off >>= 1) {
        numt += __shfl_down(numt, off);
        dent += __shfl_down(dent, off);
    }
    if (lane == 0) { red[0][wv] = numt; red[1][wv] = dent; }
    __syncthreads();
    if (tid == 0) {
        float a = (red[0][0] + red[0][1]) + (red[0][2] + red[0][3]);
        float d = (red[1][0] + red[1][1]) + (red[1][2] + red[1][3]);
        partials[blockIdx.x] = make_float2(a, d);
    }
}

__global__ __launch_bounds__(256)
void final_kernel(const float2* __restrict__ partials, float* __restrict__ out) {
    __shared__ double sa[4], sd_[4];
    int tid = threadIdx.x, lane = tid & 63, wv = tid >> 6;
    double a = 0.0, d = 0.0;
    for (int i = tid; i < NBLK; i += 256) {
        float2 p = partials[i];
        a += (double)p.x; d += (double)p.y;
    }
    #pragma unroll
    for (int off = 32; off; off >>= 1) {
        a += __shfl_down(a, off);
        d += __shfl_down(d, off);
    }
    if (lane == 0) { sa[wv] = a; sd_[wv] = d; }
    __syncthreads();
    if (tid == 0) {
        double A = (sa[0] + sa[1]) + (sa[2] + sa[3]);
        double D = (sd_[0] + sd_[1]) + (sd_[2] + sd_[3]);
        out[0] = (float)(-(A / D) / (double)NIMG);
    }
}

extern "C" void kernel_launch(void* const* d_in, const int* in_sizes, int n_in,
                              void* d_out, int out_size, void* d_ws, size_t ws_size,
                              hipStream_t stream) {
    const float* images = (const float*)d_in[0];
    const float* segs   = (const float*)d_in[1];
    const float* rois   = (const float*)d_in[2];
    float* out = (float*)d_out;

    char* ws = (char*)d_ws;
    float2* partials = (float2*)ws;                         // 17408 B
    short* AJ    = (short*)(ws + 32768);                    // 4 MB
    short* BI    = AJ + (size_t)NIMG * PIX * RW;            // 4 MB
    float* stotF = (float*)(BI + (size_t)NIMG * PIX * RW);  // 128 KB

    prep_kernel<<<NIMG * PIX / 32, 256, 0, stream>>>(images, segs, rois, AJ, BI, stotF);
    pair_kernel<<<NBLK, 256, 0, stream>>>(AJ, BI, stotF, partials);
    final_kernel<<<1, 256, 0, stream>>>(partials, out);
}

// Round 21
// 35.600 us; speedup vs baseline: 1.0089x; 1.0089x over previous
//
#include <hip/hip_runtime.h>
#include <hip/hip_bf16.h>

// NormalizedCutLoss v15 (FINAL, best-measured: 35.65-35.70 us, absmax 0.0).
// Pipeline: prep (8 thr/pixel packing) -> pair (MFMA pair-tiles over the
// symmetric triangle of 256x256 tile-pairs, j-halved: 2176 blocks) -> final.
// Row format per pixel per side: 64 bf16 (128B) = [Gram row (K=32) | lw row (K=32)]
//  Gram row:  [S bf16 (21) | 0*11]
//  A-lw row:  [gh5|gl5|gh5|1|1|ph|pl|0*13]  g=log2e*f_j, p=-0.5*log2e*sq_j
//  B-lw row:  [fh5|fh5|fl5|th|tl|1|1|0*13]  t=-0.5*log2e*sq_i
// Per 16x16 tile: 1 MFMA Gram + 1 MFMA lw; w=exp2(lw); num+=w*Gram;
// den+=w*(stc_i+stj_j). stj double-buffered in named registers (v15 win).
// CODEGEN CLIFF NOTES (v8/v11/v12 evidence): this body spills to scratch
// (~600B/thread hidden write traffic, 4-5x slowdown) when perturbed with
// (a) prefetch via runtime-indexed ARRAYS, (b) an outer pass loop,
// (c) one-shot whole-tile staging, (d) __launch_bounds__(256,4).
// Keep: named prefetch vars, static-index arrays, (256,3).
// Measured nulls: v13 no-LDS direct-L2 (44.7), v14 j-quarters (44.4),
// v16 batched ds_reads (35.9). Atomics ban: v5->v6 was 64->46.5 us.

#define NIMG 8
#define KSEG 21
#define PIX 4096
#define HI 128
#define WI 128
#define RW 64              // shorts per pixel per side
#define LROW 72            // LDS row stride in shorts (144B)
#define JCH 32             // A-rows per staged chunk
#define NCH 4              // 128 rows / 32
#define NBLK (NIMG * 272)  // 2176
#define LOG2E 1.4426950408889634f
#define BF1 ((unsigned)0x3F80)

typedef __attribute__((ext_vector_type(8))) short s8v;
typedef __attribute__((ext_vector_type(4))) float f4v;

__device__ inline float fast_exp2(float x) {
#if __has_builtin(__builtin_amdgcn_exp2f)
    return __builtin_amdgcn_exp2f(x);
#else
    return exp2f(x);
#endif
}

__device__ inline void hilo_us(float x, unsigned& h, unsigned& l) {
    __hip_bfloat16 hb = __float2bfloat16(x);
    __hip_bfloat16 lb = __float2bfloat16(x - __bfloat162float(hb));
    h = __bfloat16_as_ushort(hb);
    l = __bfloat16_as_ushort(lb);
}
__device__ inline unsigned bf16u(float x) {
    return __bfloat16_as_ushort(__float2bfloat16(x));
}
__device__ inline int pk(unsigned lo, unsigned hi) { return (int)(lo | (hi << 16)); }

__device__ inline void decode_tile(int bid, int& img, int& I, int& J, int& jh, bool& diag) {
    img = bid & 7;
    int rest = bid >> 3;
    int tp = rest >> 1; jh = rest & 1;
    if (tp >= 120) { I = J = tp - 120; diag = true; }
    else {
        diag = false;
        int t = tp; I = 0;
        while (t >= 15 - I) { t -= 15 - I; ++I; }
        J = I + 1 + t;
    }
}

// ---- prep: 8 threads per pixel, 32 pixels per 256-thread block ----
__global__ __launch_bounds__(256)
void prep_kernel(const float* __restrict__ images,
                 const float* __restrict__ segs,
                 const float* __restrict__ rois,
                 short* __restrict__ AJ,
                 short* __restrict__ BI,
                 float* __restrict__ stotF) {
    __shared__ short svL[32][24];
    int tid = threadIdx.x;
    int pxl = tid >> 3, t = tid & 7;
    int p = blockIdx.x * 32 + pxl;
    int img = p >> 12, pp = p & 4095;
    int y = pp >> 6, x = pp & 63;
    int yi = 2 * y, xi = 2 * x;

    float roi = rois[((size_t)img * HI + yi) * WI + xi];

    const float* sbase = segs + (size_t)img * KSEG * HI * WI + (size_t)yi * WI + xi;
    float sv0, sv1, sv2 = 0.0f;
    {
        const float2* s2 = (const float2*)(sbase + (size_t)t * HI * WI);
        float2 a = s2[0], b = s2[WI / 2];
        sv0 = 0.25f * ((a.x + a.y) + (b.x + b.y)) * roi;
    }
    {
        const float2* s2 = (const float2*)(sbase + (size_t)(t + 8) * HI * WI);
        float2 a = s2[0], b = s2[WI / 2];
        sv1 = 0.25f * ((a.x + a.y) + (b.x + b.y)) * roi;
    }
    if (t < 5) {
        const float2* s2 = (const float2*)(sbase + (size_t)(t + 16) * HI * WI);
        float2 a = s2[0], b = s2[WI / 2];
        sv2 = 0.25f * ((a.x + a.y) + (b.x + b.y)) * roi;
    }
    float st = sv0 + sv1 + sv2;
    st += __shfl_xor(st, 1);
    st += __shfl_xor(st, 2);
    st += __shfl_xor(st, 4);
    if (t == 0) stotF[p] = st;

    svL[pxl][t] = (short)bf16u(sv0);
    svL[pxl][t + 8] = (short)bf16u(sv1);
    if (t < 5) svL[pxl][t + 16] = (short)bf16u(sv2);
    if (t == 7) { svL[pxl][21] = 0; svL[pxl][22] = 0; svL[pxl][23] = 0; }

    const float* im = images + (size_t)img * 3 * HI * WI;
    float f0 = im[yi * WI + xi] * (1.0f / 15.0f);
    float f1 = im[HI * WI + yi * WI + xi] * (1.0f / 15.0f);
    float f2 = im[2 * HI * WI + yi * WI + xi] * (1.0f / 15.0f);
    float f3 = (float)x * (1.0f / 40.0f);
    float f4 = (float)y * (1.0f / 40.0f);
    float sq = f0*f0 + f1*f1 + f2*f2 + f3*f3 + f4*f4;
    float q = -0.5f * sq * LOG2E;
    unsigned qh, ql; hilo_us(q, qh, ql);
    unsigned fh[5], fl[5], gh[5], gl[5];
    float fa[5] = {f0, f1, f2, f3, f4};
    #pragma unroll
    for (int c = 0; c < 5; ++c) {
        hilo_us(fa[c], fh[c], fl[c]);
        hilo_us(fa[c] * LOG2E, gh[c], gl[c]);
    }

    int4 zq = {0, 0, 0, 0};
    int4 qA0 = { pk(gh[0],gh[1]), pk(gh[2],gh[3]), pk(gh[4],gl[0]), pk(gl[1],gl[2]) };
    int4 qA1 = { pk(gl[3],gl[4]), pk(gh[0],gh[1]), pk(gh[2],gh[3]), pk(gh[4],BF1) };
    int4 qA2 = { pk(BF1,qh), pk(ql,0), 0, 0 };
    int4 qB0 = { pk(fh[0],fh[1]), pk(fh[2],fh[3]), pk(fh[4],fh[0]), pk(fh[1],fh[2]) };
    int4 qB1 = { pk(fh[3],fh[4]), pk(fl[0],fl[1]), pk(fl[2],fl[3]), pk(fl[4],qh) };
    int4 qB2 = { pk(ql,BF1), pk(BF1,0), 0, 0 };

    __syncthreads();

    int tg = (t < 3) ? t : 0;
    int4 gq = *(const int4*)(&svL[pxl][tg * 8]);

    int4 outA = (t < 3) ? gq : (t == 4) ? qA0 : (t == 5) ? qA1 : (t == 6) ? qA2 : zq;
    int4 outB = (t < 3) ? gq : (t == 4) ? qB0 : (t == 5) ? qB1 : (t == 6) ? qB2 : zq;

    *(int4*)(AJ + (size_t)p * RW + t * 8) = outA;
    *(int4*)(BI + (size_t)p * RW + t * 8) = outB;
}

// ---- pair: v10 body + stj double-buffer in named registers (v15) ----
__global__ __launch_bounds__(256, 3)
void pair_kernel(const short* __restrict__ AJ,
                 const short* __restrict__ BI,
                 const float* __restrict__ stotF,
                 float2* __restrict__ partials) {
    __shared__ __align__(16) short stage[2][JCH * LROW];
    __shared__ float red[2][4];

    int tid = threadIdx.x, lane = tid & 63, wv = tid >> 6;
    int c = lane & 15, sg = lane >> 4;
    int img, I, J, jh; bool diag;
    decode_tile(blockIdx.x, img, I, J, jh, diag);
    size_t ibase = (size_t)img * PIX + I * 256;
    size_t jbase = (size_t)img * PIX + J * 256 + jh * 128;
    int i0 = wv * 64;

    s8v bg[4], bl[4];
    float stc[4];
    #pragma unroll
    for (int r = 0; r < 4; ++r) {
        const short* bp = BI + (ibase + i0 + r * 16 + c) * RW;
        bg[r] = *(const s8v*)(bp + sg * 8);
        bl[r] = *(const s8v*)(bp + 32 + sg * 8);
        stc[r] = stotF[ibase + i0 + r * 16 + c];
    }

    const short* ajg = AJ + jbase * RW;
    const float* stjp = stotF + jbase + sg * 4;   // per-lane stj pointer
    f4v zf = {0.0f, 0.0f, 0.0f, 0.0f};

    int row0 = tid >> 3, ch0 = tid & 7;
    auto stage_chunk = [&](int chk, int buf) {
        const short* base = ajg + (size_t)chk * JCH * RW;
        *(float4*)(&stage[buf][row0 * LROW + ch0 * 8]) =
            *(const float4*)(base + row0 * RW + ch0 * 8);
    };

    float num[4] = {0,0,0,0}, den[4] = {0,0,0,0};

    // Prologue: stage chunk 0 and prefetch chunk 0's two stj vectors (named regs).
    stage_chunk(0, 0);
    f4v sjc0 = diag ? zf : *(const f4v*)(stjp);
    f4v sjc1 = diag ? zf : *(const f4v*)(stjp + 16);

    for (int chk = 0; chk < NCH; ++chk) {
        int buf = chk & 1;
        __syncthreads();
        f4v sjn0 = zf, sjn1 = zf;
        if (chk + 1 < NCH) {
            stage_chunk(chk + 1, buf ^ 1);
            if (!diag) {
                sjn0 = *(const f4v*)(stjp + (chk + 1) * 32);
                sjn1 = *(const f4v*)(stjp + (chk + 1) * 32 + 16);
            }
        }
        #pragma unroll
        for (int jtl = 0; jtl < 2; ++jtl) {
            const short* rb = &stage[buf][(jtl * 16 + c) * LROW];
            s8v ag = *(const s8v*)(rb + sg * 8);
            s8v al = *(const s8v*)(rb + 32 + sg * 8);
            f4v stj4 = (jtl == 0) ? sjc0 : sjc1;

            f4v z = {0, 0, 0, 0};
            f4v g[4], lw[4];
            #pragma unroll
            for (int r = 0; r < 4; ++r) g[r]  = __builtin_amdgcn_mfma_f32_16x16x32_bf16(ag, bg[r], z, 0, 0, 0);
            #pragma unroll
            for (int r = 0; r < 4; ++r) lw[r] = __builtin_amdgcn_mfma_f32_16x16x32_bf16(al, bl[r], z, 0, 0, 0);

            #pragma unroll
            for (int r = 0; r < 4; ++r) {
                #pragma unroll
                for (int qd = 0; qd < 4; ++qd) {
                    float w = fast_exp2(lw[r][qd]);
                    num[r] = fmaf(w, g[r][qd], num[r]);
                    den[r] = fmaf(w, stc[r] + stj4[qd], den[r]);
                }
            }
        }
        sjc0 = sjn0; sjc1 = sjn1;
    }

    float numt = (num[0] + num[1]) + (num[2] + num[3]);
    float dent = (den[0] + den[1]) + (den[2] + den[3]);
    if (!diag) numt *= 2.0f;

    #pragma unroll
    for (int off = 32; off; off >>= 1) {
        numt += __shfl_down(numt, off);
        dent += __shfl_down(dent, off);
    }
    if (lane == 0) { red[0][wv] = numt; red[1][wv] = dent; }
    __syncthreads();
    if (tid == 0) {
        float a = (red[0][0] + red[0][1]) + (red[0][2] + red[0][3]);
        float d = (red[1][0] + red[1][1]) + (red[1][2] + red[1][3]);
        partials[blockIdx.x] = make_float2(a, d);
    }
}

__global__ __launch_bounds__(256)
void final_kernel(const float2* __restrict__ partials, float* __restrict__ out) {
    __shared__ double sa[4], sd_[4];
    int tid = threadIdx.x, lane = tid & 63, wv = tid >> 6;
    double a = 0.0, d = 0.0;
    for (int i = tid; i < NBLK; i += 256) {
        float2 p = partials[i];
        a += (double)p.x; d += (double)p.y;
    }
    #pragma unroll
    for (int off = 32; off; off >>= 1) {
        a += __shfl_down(a, off);
        d += __shfl_down(d, off);
    }
    if (lane == 0) { sa[wv] = a; sd_[wv] = d; }
    __syncthreads();
    if (tid == 0) {
        double A = (sa[0] + sa[1]) + (sa[2] + sa[3]);
        double D = (sd_[0] + sd_[1]) + (sd_[2] + sd_[3]);
        out[0] = (float)(-(A / D) / (double)NIMG);
    }
}

extern "C" void kernel_launch(void* const* d_in, const int* in_sizes, int n_in,
                              void* d_out, int out_size, void* d_ws, size_t ws_size,
                              hipStream_t stream) {
    const float* images = (const float*)d_in[0];
    const float* segs   = (const float*)d_in[1];
    const float* rois   = (const float*)d_in[2];
    float* out = (float*)d_out;

    char* ws = (char*)d_ws;
    float2* partials = (float2*)ws;                         // 17408 B
    short* AJ    = (short*)(ws + 32768);                    // 4 MB
    short* BI    = AJ + (size_t)NIMG * PIX * RW;            // 4 MB
    float* stotF = (float*)(BI + (size_t)NIMG * PIX * RW);  // 128 KB

    prep_kernel<<<NIMG * PIX / 32, 256, 0, stream>>>(images, segs, rois, AJ, BI, stotF);
    pair_kernel<<<NBLK, 256, 0, stream>>>(AJ, BI, stotF, partials);
    final_kernel<<<1, 256, 0, stream>>>(partials, out);
}

// Round 22
// 35.578 us; speedup vs baseline: 1.0094x; 1.0006x over previous
//
#include <hip/hip_runtime.h>
#include <hip/hip_bf16.h>

// NormalizedCutLoss v15 (FINAL, best-measured: 35.60-35.70 us over 3 runs, absmax 0.0).
// Pipeline: prep (8 thr/pixel packing) -> pair (MFMA pair-tiles over the
// symmetric triangle of 256x256 tile-pairs, j-halved: 2176 blocks) -> final.
// Row format per pixel per side: 64 bf16 (128B) = [Gram row (K=32) | lw row (K=32)]
//  Gram row:  [S bf16 (21) | 0*11]
//  A-lw row:  [gh5|gl5|gh5|1|1|ph|pl|0*13]  g=log2e*f_j, p=-0.5*log2e*sq_j
//  B-lw row:  [fh5|fh5|fl5|th|tl|1|1|0*13]  t=-0.5*log2e*sq_i
// Per 16x16 tile: 1 MFMA Gram + 1 MFMA lw; w=exp2(lw); num+=w*Gram;
// den+=w*(stc_i+stj_j). stj double-buffered in named registers (v15 win, -1.2us).
// CODEGEN CLIFF NOTES (v8/v11/v12 evidence): this body spills to scratch
// (~600B/thread hidden write traffic, 4-5x slowdown) when perturbed with
// (a) prefetch via runtime-indexed ARRAYS, (b) an outer pass loop,
// (c) one-shot whole-tile staging. Keep: named prefetch vars,
// static-index arrays, (256,3).
// Measured nulls: v13 no-LDS direct-L2 (44.7), v14 j-quarters (44.4),
// v16 batched ds_reads (35.9). Atomics ban: v5->v6 was 64->46.5 us.
// Plateau statement: pair ~22us vs ~7.5us VALU-issue floor; latency-exposure
// bound at ~2-3 effective waves/SIMD; 8 restructures measured null/regression.

#define NIMG 8
#define KSEG 21
#define PIX 4096
#define HI 128
#define WI 128
#define RW 64              // shorts per pixel per side
#define LROW 72            // LDS row stride in shorts (144B)
#define JCH 32             // A-rows per staged chunk
#define NCH 4              // 128 rows / 32
#define NBLK (NIMG * 272)  // 2176
#define LOG2E 1.4426950408889634f
#define BF1 ((unsigned)0x3F80)

typedef __attribute__((ext_vector_type(8))) short s8v;
typedef __attribute__((ext_vector_type(4))) float f4v;

__device__ inline float fast_exp2(float x) {
#if __has_builtin(__builtin_amdgcn_exp2f)
    return __builtin_amdgcn_exp2f(x);
#else
    return exp2f(x);
#endif
}

__device__ inline void hilo_us(float x, unsigned& h, unsigned& l) {
    __hip_bfloat16 hb = __float2bfloat16(x);
    __hip_bfloat16 lb = __float2bfloat16(x - __bfloat162float(hb));
    h = __bfloat16_as_ushort(hb);
    l = __bfloat16_as_ushort(lb);
}
__device__ inline unsigned bf16u(float x) {
    return __bfloat16_as_ushort(__float2bfloat16(x));
}
__device__ inline int pk(unsigned lo, unsigned hi) { return (int)(lo | (hi << 16)); }

__device__ inline void decode_tile(int bid, int& img, int& I, int& J, int& jh, bool& diag) {
    img = bid & 7;
    int rest = bid >> 3;
    int tp = rest >> 1; jh = rest & 1;
    if (tp >= 120) { I = J = tp - 120; diag = true; }
    else {
        diag = false;
        int t = tp; I = 0;
        while (t >= 15 - I) { t -= 15 - I; ++I; }
        J = I + 1 + t;
    }
}

// ---- prep: 8 threads per pixel, 32 pixels per 256-thread block ----
__global__ __launch_bounds__(256)
void prep_kernel(const float* __restrict__ images,
                 const float* __restrict__ segs,
                 const float* __restrict__ rois,
                 short* __restrict__ AJ,
                 short* __restrict__ BI,
                 float* __restrict__ stotF) {
    __shared__ short svL[32][24];
    int tid = threadIdx.x;
    int pxl = tid >> 3, t = tid & 7;
    int p = blockIdx.x * 32 + pxl;
    int img = p >> 12, pp = p & 4095;
    int y = pp >> 6, x = pp & 63;
    int yi = 2 * y, xi = 2 * x;

    float roi = rois[((size_t)img * HI + yi) * WI + xi];

    const float* sbase = segs + (size_t)img * KSEG * HI * WI + (size_t)yi * WI + xi;
    float sv0, sv1, sv2 = 0.0f;
    {
        const float2* s2 = (const float2*)(sbase + (size_t)t * HI * WI);
        float2 a = s2[0], b = s2[WI / 2];
        sv0 = 0.25f * ((a.x + a.y) + (b.x + b.y)) * roi;
    }
    {
        const float2* s2 = (const float2*)(sbase + (size_t)(t + 8) * HI * WI);
        float2 a = s2[0], b = s2[WI / 2];
        sv1 = 0.25f * ((a.x + a.y) + (b.x + b.y)) * roi;
    }
    if (t < 5) {
        const float2* s2 = (const float2*)(sbase + (size_t)(t + 16) * HI * WI);
        float2 a = s2[0], b = s2[WI / 2];
        sv2 = 0.25f * ((a.x + a.y) + (b.x + b.y)) * roi;
    }
    float st = sv0 + sv1 + sv2;
    st += __shfl_xor(st, 1);
    st += __shfl_xor(st, 2);
    st += __shfl_xor(st, 4);
    if (t == 0) stotF[p] = st;

    svL[pxl][t] = (short)bf16u(sv0);
    svL[pxl][t + 8] = (short)bf16u(sv1);
    if (t < 5) svL[pxl][t + 16] = (short)bf16u(sv2);
    if (t == 7) { svL[pxl][21] = 0; svL[pxl][22] = 0; svL[pxl][23] = 0; }

    const float* im = images + (size_t)img * 3 * HI * WI;
    float f0 = im[yi * WI + xi] * (1.0f / 15.0f);
    float f1 = im[HI * WI + yi * WI + xi] * (1.0f / 15.0f);
    float f2 = im[2 * HI * WI + yi * WI + xi] * (1.0f / 15.0f);
    float f3 = (float)x * (1.0f / 40.0f);
    float f4 = (float)y * (1.0f / 40.0f);
    float sq = f0*f0 + f1*f1 + f2*f2 + f3*f3 + f4*f4;
    float q = -0.5f * sq * LOG2E;
    unsigned qh, ql; hilo_us(q, qh, ql);
    unsigned fh[5], fl[5], gh[5], gl[5];
    float fa[5] = {f0, f1, f2, f3, f4};
    #pragma unroll
    for (int c = 0; c < 5; ++c) {
        hilo_us(fa[c], fh[c], fl[c]);
        hilo_us(fa[c] * LOG2E, gh[c], gl[c]);
    }

    int4 zq = {0, 0, 0, 0};
    int4 qA0 = { pk(gh[0],gh[1]), pk(gh[2],gh[3]), pk(gh[4],gl[0]), pk(gl[1],gl[2]) };
    int4 qA1 = { pk(gl[3],gl[4]), pk(gh[0],gh[1]), pk(gh[2],gh[3]), pk(gh[4],BF1) };
    int4 qA2 = { pk(BF1,qh), pk(ql,0), 0, 0 };
    int4 qB0 = { pk(fh[0],fh[1]), pk(fh[2],fh[3]), pk(fh[4],fh[0]), pk(fh[1],fh[2]) };
    int4 qB1 = { pk(fh[3],fh[4]), pk(fl[0],fl[1]), pk(fl[2],fl[3]), pk(fl[4],qh) };
    int4 qB2 = { pk(ql,BF1), pk(BF1,0), 0, 0 };

    __syncthreads();

    int tg = (t < 3) ? t : 0;
    int4 gq = *(const int4*)(&svL[pxl][tg * 8]);

    int4 outA = (t < 3) ? gq : (t == 4) ? qA0 : (t == 5) ? qA1 : (t == 6) ? qA2 : zq;
    int4 outB = (t < 3) ? gq : (t == 4) ? qB0 : (t == 5) ? qB1 : (t == 6) ? qB2 : zq;

    *(int4*)(AJ + (size_t)p * RW + t * 8) = outA;
    *(int4*)(BI + (size_t)p * RW + t * 8) = outB;
}

// ---- pair: v10 body + stj double-buffer in named registers (v15) ----
__global__ __launch_bounds__(256, 3)
void pair_kernel(const short* __restrict__ AJ,
                 const short* __restrict__ BI,
                 const float* __restrict__ stotF,
                 float2* __restrict__ partials) {
    __shared__ __align__(16) short stage[2][JCH * LROW];
    __shared__ float red[2][4];

    int tid = threadIdx.x, lane = tid & 63, wv = tid >> 6;
    int c = lane & 15, sg = lane >> 4;
    int img, I, J, jh; bool diag;
    decode_tile(blockIdx.x, img, I, J, jh, diag);
    size_t ibase = (size_t)img * PIX + I * 256;
    size_t jbase = (size_t)img * PIX + J * 256 + jh * 128;
    int i0 = wv * 64;

    s8v bg[4], bl[4];
    float stc[4];
    #pragma unroll
    for (int r = 0; r < 4; ++r) {
        const short* bp = BI + (ibase + i0 + r * 16 + c) * RW;
        bg[r] = *(const s8v*)(bp + sg * 8);
        bl[r] = *(const s8v*)(bp + 32 + sg * 8);
        stc[r] = stotF[ibase + i0 + r * 16 + c];
    }

    const short* ajg = AJ + jbase * RW;
    const float* stjp = stotF + jbase + sg * 4;   // per-lane stj pointer
    f4v zf = {0.0f, 0.0f, 0.0f, 0.0f};

    int row0 = tid >> 3, ch0 = tid & 7;
    auto stage_chunk = [&](int chk, int buf) {
        const short* base = ajg + (size_t)chk * JCH * RW;
        *(float4*)(&stage[buf][row0 * LROW + ch0 * 8]) =
            *(const float4*)(base + row0 * RW + ch0 * 8);
    };

    float num[4] = {0,0,0,0}, den[4] = {0,0,0,0};

    // Prologue: stage chunk 0 and prefetch chunk 0's two stj vectors (named regs).
    stage_chunk(0, 0);
    f4v sjc0 = diag ? zf : *(const f4v*)(stjp);
    f4v sjc1 = diag ? zf : *(const f4v*)(stjp + 16);

    for (int chk = 0; chk < NCH; ++chk) {
        int buf = chk & 1;
        __syncthreads();
        f4v sjn0 = zf, sjn1 = zf;
        if (chk + 1 < NCH) {
            stage_chunk(chk + 1, buf ^ 1);
            if (!diag) {
                sjn0 = *(const f4v*)(stjp + (chk + 1) * 32);
                sjn1 = *(const f4v*)(stjp + (chk + 1) * 32 + 16);
            }
        }
        #pragma unroll
        for (int jtl = 0; jtl < 2; ++jtl) {
            const short* rb = &stage[buf][(jtl * 16 + c) * LROW];
            s8v ag = *(const s8v*)(rb + sg * 8);
            s8v al = *(const s8v*)(rb + 32 + sg * 8);
            f4v stj4 = (jtl == 0) ? sjc0 : sjc1;

            f4v z = {0, 0, 0, 0};
            f4v g[4], lw[4];
            #pragma unroll
            for (int r = 0; r < 4; ++r) g[r]  = __builtin_amdgcn_mfma_f32_16x16x32_bf16(ag, bg[r], z, 0, 0, 0);
            #pragma unroll
            for (int r = 0; r < 4; ++r) lw[r] = __builtin_amdgcn_mfma_f32_16x16x32_bf16(al, bl[r], z, 0, 0, 0);

            #pragma unroll
            for (int r = 0; r < 4; ++r) {
                #pragma unroll
                for (int qd = 0; qd < 4; ++qd) {
                    float w = fast_exp2(lw[r][qd]);
                    num[r] = fmaf(w, g[r][qd], num[r]);
                    den[r] = fmaf(w, stc[r] + stj4[qd], den[r]);
                }
            }
        }
        sjc0 = sjn0; sjc1 = sjn1;
    }

    float numt = (num[0] + num[1]) + (num[2] + num[3]);
    float dent = (den[0] + den[1]) + (den[2] + den[3]);
    if (!diag) numt *= 2.0f;

    #pragma unroll
    for (int off = 32; off; off >>= 1) {
        numt += __shfl_down(numt, off);
        dent += __shfl_down(dent, off);
    }
    if (lane == 0) { red[0][wv] = numt; red[1][wv] = dent; }
    __syncthreads();
    if (tid == 0) {
        float a = (red[0][0] + red[0][1]) + (red[0][2] + red[0][3]);
        float d = (red[1][0] + red[1][1]) + (red[1][2] + red[1][3]);
        partials[blockIdx.x] = make_float2(a, d);
    }
}

__global__ __launch_bounds__(256)
void final_kernel(const float2* __restrict__ partials, float* __restrict__ out) {
    __shared__ double sa[4], sd_[4];
    int tid = threadIdx.x, lane = tid & 63, wv = tid >> 6;
    double a = 0.0, d = 0.0;
    for (int i = tid; i < NBLK; i += 256) {
        float2 p = partials[i];
        a += (double)p.x; d += (double)p.y;
    }
    #pragma unroll
    for (int off = 32; off; off >>= 1) {
        a += __shfl_down(a, off);
        d += __shfl_down(d, off);
    }
    if (lane == 0) { sa[wv] = a; sd_[wv] = d; }
    __syncthreads();
    if (tid == 0) {
        double A = (sa[0] + sa[1]) + (sa[2] + sa[3]);
        double D = (sd_[0] + sd_[1]) + (sd_[2] + sd_[3]);
        out[0] = (float)(-(A / D) / (double)NIMG);
    }
}

extern "C" void kernel_launch(void* const* d_in, const int* in_sizes, int n_in,
                              void* d_out, int out_size, void* d_ws, size_t ws_size,
                              hipStream_t stream) {
    const float* images = (const float*)d_in[0];
    const float* segs   = (const float*)d_in[1];
    const float* rois   = (const float*)d_in[2];
    float* out = (float*)d_out;

    char* ws = (char*)d_ws;
    float2* partials = (float2*)ws;                         // 17408 B
    short* AJ    = (short*)(ws + 32768);                    // 4 MB
    short* BI    = AJ + (size_t)NIMG * PIX * RW;            // 4 MB
    float* stotF = (float*)(BI + (size_t)NIMG * PIX * RW);  // 128 KB

    prep_kernel<<<NIMG * PIX / 32, 256, 0, stream>>>(images, segs, rois, AJ, BI, stotF);
    pair_kernel<<<NBLK, 256, 0, stream>>>(AJ, BI, stotF, partials);
    final_kernel<<<1, 256, 0, stream>>>(partials, out);
}

// Round 23
// 35.401 us; speedup vs baseline: 1.0145x; 1.0050x over previous
//
#include <hip/hip_runtime.h>
#include <hip/hip_bf16.h>

// NormalizedCutLoss v17 = v15 + ONE change: s_setprio(1) around the 8-MFMA
// cluster per jtl (T5). Zero extra registers -> no spill-cliff exposure.
// Mechanism: 3 independent blocks/CU sit at different phases; priority boost
// lets MFMA-phase waves preempt staging-phase waves' issue slots (attn-analog
// m191 +4-7%; null only on lockstep single-block-phase GEMM m190).
// CODEGEN CLIFF NOTES (v8/v11/v12): NO runtime-indexed prefetch arrays,
// NO outer pass loop, NO one-shot whole-tile staging. Keep (256,3).
// Measured: v15 = 35.58-35.70us x4 runs; v16 batched ds_reads 35.9 (null).

#define NIMG 8
#define KSEG 21
#define PIX 4096
#define HI 128
#define WI 128
#define RW 64              // shorts per pixel per side
#define LROW 72            // LDS row stride in shorts (144B)
#define JCH 32             // A-rows per staged chunk
#define NCH 4              // 128 rows / 32
#define NBLK (NIMG * 272)  // 2176
#define LOG2E 1.4426950408889634f
#define BF1 ((unsigned)0x3F80)

typedef __attribute__((ext_vector_type(8))) short s8v;
typedef __attribute__((ext_vector_type(4))) float f4v;

__device__ inline float fast_exp2(float x) {
#if __has_builtin(__builtin_amdgcn_exp2f)
    return __builtin_amdgcn_exp2f(x);
#else
    return exp2f(x);
#endif
}

__device__ inline void hilo_us(float x, unsigned& h, unsigned& l) {
    __hip_bfloat16 hb = __float2bfloat16(x);
    __hip_bfloat16 lb = __float2bfloat16(x - __bfloat162float(hb));
    h = __bfloat16_as_ushort(hb);
    l = __bfloat16_as_ushort(lb);
}
__device__ inline unsigned bf16u(float x) {
    return __bfloat16_as_ushort(__float2bfloat16(x));
}
__device__ inline int pk(unsigned lo, unsigned hi) { return (int)(lo | (hi << 16)); }

__device__ inline void decode_tile(int bid, int& img, int& I, int& J, int& jh, bool& diag) {
    img = bid & 7;
    int rest = bid >> 3;
    int tp = rest >> 1; jh = rest & 1;
    if (tp >= 120) { I = J = tp - 120; diag = true; }
    else {
        diag = false;
        int t = tp; I = 0;
        while (t >= 15 - I) { t -= 15 - I; ++I; }
        J = I + 1 + t;
    }
}

// ---- prep: 8 threads per pixel, 32 pixels per 256-thread block ----
__global__ __launch_bounds__(256)
void prep_kernel(const float* __restrict__ images,
                 const float* __restrict__ segs,
                 const float* __restrict__ rois,
                 short* __restrict__ AJ,
                 short* __restrict__ BI,
                 float* __restrict__ stotF) {
    __shared__ short svL[32][24];
    int tid = threadIdx.x;
    int pxl = tid >> 3, t = tid & 7;
    int p = blockIdx.x * 32 + pxl;
    int img = p >> 12, pp = p & 4095;
    int y = pp >> 6, x = pp & 63;
    int yi = 2 * y, xi = 2 * x;

    float roi = rois[((size_t)img * HI + yi) * WI + xi];

    const float* sbase = segs + (size_t)img * KSEG * HI * WI + (size_t)yi * WI + xi;
    float sv0, sv1, sv2 = 0.0f;
    {
        const float2* s2 = (const float2*)(sbase + (size_t)t * HI * WI);
        float2 a = s2[0], b = s2[WI / 2];
        sv0 = 0.25f * ((a.x + a.y) + (b.x + b.y)) * roi;
    }
    {
        const float2* s2 = (const float2*)(sbase + (size_t)(t + 8) * HI * WI);
        float2 a = s2[0], b = s2[WI / 2];
        sv1 = 0.25f * ((a.x + a.y) + (b.x + b.y)) * roi;
    }
    if (t < 5) {
        const float2* s2 = (const float2*)(sbase + (size_t)(t + 16) * HI * WI);
        float2 a = s2[0], b = s2[WI / 2];
        sv2 = 0.25f * ((a.x + a.y) + (b.x + b.y)) * roi;
    }
    float st = sv0 + sv1 + sv2;
    st += __shfl_xor(st, 1);
    st += __shfl_xor(st, 2);
    st += __shfl_xor(st, 4);
    if (t == 0) stotF[p] = st;

    svL[pxl][t] = (short)bf16u(sv0);
    svL[pxl][t + 8] = (short)bf16u(sv1);
    if (t < 5) svL[pxl][t + 16] = (short)bf16u(sv2);
    if (t == 7) { svL[pxl][21] = 0; svL[pxl][22] = 0; svL[pxl][23] = 0; }

    const float* im = images + (size_t)img * 3 * HI * WI;
    float f0 = im[yi * WI + xi] * (1.0f / 15.0f);
    float f1 = im[HI * WI + yi * WI + xi] * (1.0f / 15.0f);
    float f2 = im[2 * HI * WI + yi * WI + xi] * (1.0f / 15.0f);
    float f3 = (float)x * (1.0f / 40.0f);
    float f4 = (float)y * (1.0f / 40.0f);
    float sq = f0*f0 + f1*f1 + f2*f2 + f3*f3 + f4*f4;
    float q = -0.5f * sq * LOG2E;
    unsigned qh, ql; hilo_us(q, qh, ql);
    unsigned fh[5], fl[5], gh[5], gl[5];
    float fa[5] = {f0, f1, f2, f3, f4};
    #pragma unroll
    for (int c = 0; c < 5; ++c) {
        hilo_us(fa[c], fh[c], fl[c]);
        hilo_us(fa[c] * LOG2E, gh[c], gl[c]);
    }

    int4 zq = {0, 0, 0, 0};
    int4 qA0 = { pk(gh[0],gh[1]), pk(gh[2],gh[3]), pk(gh[4],gl[0]), pk(gl[1],gl[2]) };
    int4 qA1 = { pk(gl[3],gl[4]), pk(gh[0],gh[1]), pk(gh[2],gh[3]), pk(gh[4],BF1) };
    int4 qA2 = { pk(BF1,qh), pk(ql,0), 0, 0 };
    int4 qB0 = { pk(fh[0],fh[1]), pk(fh[2],fh[3]), pk(fh[4],fh[0]), pk(fh[1],fh[2]) };
    int4 qB1 = { pk(fh[3],fh[4]), pk(fl[0],fl[1]), pk(fl[2],fl[3]), pk(fl[4],qh) };
    int4 qB2 = { pk(ql,BF1), pk(BF1,0), 0, 0 };

    __syncthreads();

    int tg = (t < 3) ? t : 0;
    int4 gq = *(const int4*)(&svL[pxl][tg * 8]);

    int4 outA = (t < 3) ? gq : (t == 4) ? qA0 : (t == 5) ? qA1 : (t == 6) ? qA2 : zq;
    int4 outB = (t < 3) ? gq : (t == 4) ? qB0 : (t == 5) ? qB1 : (t == 6) ? qB2 : zq;

    *(int4*)(AJ + (size_t)p * RW + t * 8) = outA;
    *(int4*)(BI + (size_t)p * RW + t * 8) = outB;
}

// ---- pair: v15 body + s_setprio(1) around the MFMA cluster ----
__global__ __launch_bounds__(256, 3)
void pair_kernel(const short* __restrict__ AJ,
                 const short* __restrict__ BI,
                 const float* __restrict__ stotF,
                 float2* __restrict__ partials) {
    __shared__ __align__(16) short stage[2][JCH * LROW];
    __shared__ float red[2][4];

    int tid = threadIdx.x, lane = tid & 63, wv = tid >> 6;
    int c = lane & 15, sg = lane >> 4;
    int img, I, J, jh; bool diag;
    decode_tile(blockIdx.x, img, I, J, jh, diag);
    size_t ibase = (size_t)img * PIX + I * 256;
    size_t jbase = (size_t)img * PIX + J * 256 + jh * 128;
    int i0 = wv * 64;

    s8v bg[4], bl[4];
    float stc[4];
    #pragma unroll
    for (int r = 0; r < 4; ++r) {
        const short* bp = BI + (ibase + i0 + r * 16 + c) * RW;
        bg[r] = *(const s8v*)(bp + sg * 8);
        bl[r] = *(const s8v*)(bp + 32 + sg * 8);
        stc[r] = stotF[ibase + i0 + r * 16 + c];
    }

    const short* ajg = AJ + jbase * RW;
    const float* stjp = stotF + jbase + sg * 4;   // per-lane stj pointer
    f4v zf = {0.0f, 0.0f, 0.0f, 0.0f};

    int row0 = tid >> 3, ch0 = tid & 7;
    auto stage_chunk = [&](int chk, int buf) {
        const short* base = ajg + (size_t)chk * JCH * RW;
        *(float4*)(&stage[buf][row0 * LROW + ch0 * 8]) =
            *(const float4*)(base + row0 * RW + ch0 * 8);
    };

    float num[4] = {0,0,0,0}, den[4] = {0,0,0,0};

    // Prologue: stage chunk 0 and prefetch chunk 0's two stj vectors (named regs).
    stage_chunk(0, 0);
    f4v sjc0 = diag ? zf : *(const f4v*)(stjp);
    f4v sjc1 = diag ? zf : *(const f4v*)(stjp + 16);

    for (int chk = 0; chk < NCH; ++chk) {
        int buf = chk & 1;
        __syncthreads();
        f4v sjn0 = zf, sjn1 = zf;
        if (chk + 1 < NCH) {
            stage_chunk(chk + 1, buf ^ 1);
            if (!diag) {
                sjn0 = *(const f4v*)(stjp + (chk + 1) * 32);
                sjn1 = *(const f4v*)(stjp + (chk + 1) * 32 + 16);
            }
        }
        #pragma unroll
        for (int jtl = 0; jtl < 2; ++jtl) {
            const short* rb = &stage[buf][(jtl * 16 + c) * LROW];
            s8v ag = *(const s8v*)(rb + sg * 8);
            s8v al = *(const s8v*)(rb + 32 + sg * 8);
            f4v stj4 = (jtl == 0) ? sjc0 : sjc1;

            f4v z = {0, 0, 0, 0};
            f4v g[4], lw[4];
            __builtin_amdgcn_s_setprio(1);
            #pragma unroll
            for (int r = 0; r < 4; ++r) g[r]  = __builtin_amdgcn_mfma_f32_16x16x32_bf16(ag, bg[r], z, 0, 0, 0);
            #pragma unroll
            for (int r = 0; r < 4; ++r) lw[r] = __builtin_amdgcn_mfma_f32_16x16x32_bf16(al, bl[r], z, 0, 0, 0);
            __builtin_amdgcn_s_setprio(0);

            #pragma unroll
            for (int r = 0; r < 4; ++r) {
                #pragma unroll
                for (int qd = 0; qd < 4; ++qd) {
                    float w = fast_exp2(lw[r][qd]);
                    num[r] = fmaf(w, g[r][qd], num[r]);
                    den[r] = fmaf(w, stc[r] + stj4[qd], den[r]);
                }
            }
        }
        sjc0 = sjn0; sjc1 = sjn1;
    }

    float numt = (num[0] + num[1]) + (num[2] + num[3]);
    float dent = (den[0] + den[1]) + (den[2] + den[3]);
    if (!diag) numt *= 2.0f;

    #pragma unroll
    for (int off = 32; off; off >>= 1) {
        numt += __shfl_down(numt, off);
        dent += __shfl_down(dent, off);
    }
    if (lane == 0) { red[0][wv] = numt; red[1][wv] = dent; }
    __syncthreads();
    if (tid == 0) {
        float a = (red[0][0] + red[0][1]) + (red[0][2] + red[0][3]);
        float d = (red[1][0] + red[1][1]) + (red[1][2] + red[1][3]);
        partials[blockIdx.x] = make_float2(a, d);
    }
}

__global__ __launch_bounds__(256)
void final_kernel(const float2* __restrict__ partials, float* __restrict__ out) {
    __shared__ double sa[4], sd_[4];
    int tid = threadIdx.x, lane = tid & 63, wv = tid >> 6;
    double a = 0.0, d = 0.0;
    for (int i = tid; i < NBLK; i += 256) {
        float2 p = partials[i];
        a += (double)p.x; d += (double)p.y;
    }
    #pragma unroll
    for (int off = 32; off; off >>= 1) {
        a += __shfl_down(a, off);
        d += __shfl_down(d, off);
    }
    if (lane == 0) { sa[wv] = a; sd_[wv] = d; }
    __syncthreads();
    if (tid == 0) {
        double A = (sa[0] + sa[1]) + (sa[2] + sa[3]);
        double D = (sd_[0] + sd_[1]) + (sd_[2] + sd_[3]);
        out[0] = (float)(-(A / D) / (double)NIMG);
    }
}

extern "C" void kernel_launch(void* const* d_in, const int* in_sizes, int n_in,
                              void* d_out, int out_size, void* d_ws, size_t ws_size,
                              hipStream_t stream) {
    const float* images = (const float*)d_in[0];
    const float* segs   = (const float*)d_in[1];
    const float* rois   = (const float*)d_in[2];
    float* out = (float*)d_out;

    char* ws = (char*)d_ws;
    float2* partials = (float2*)ws;                         // 17408 B
    short* AJ    = (short*)(ws + 32768);                    // 4 MB
    short* BI    = AJ + (size_t)NIMG * PIX * RW;            // 4 MB
    float* stotF = (float*)(BI + (size_t)NIMG * PIX * RW);  // 128 KB

    prep_kernel<<<NIMG * PIX / 32, 256, 0, stream>>>(images, segs, rois, AJ, BI, stotF);
    pair_kernel<<<NBLK, 256, 0, stream>>>(AJ, BI, stotF, partials);
    final_kernel<<<1, 256, 0, stream>>>(partials, out);
}